// Round 4
// baseline (4466.239 us; speedup 1.0000x reference)
//
#include <hip/hip_runtime.h>
#include <math.h>

#define NB    8
#define NE    1024
#define DDIM  256
#define TTOK  4096
#define BBATCH 16
#define NTOK  (BBATCH*TTOK)   // 65536

#define TM    64      // tokens per block
#define RSTR  260     // res_s row stride (floats), 16B aligned
#define EPS_GAP 1e-4f // certify threshold: approx top-2 gap below this -> exact rescore

typedef _Float16 half8 __attribute__((ext_vector_type(8)));
typedef float f32x4 __attribute__((ext_vector_type(4)));

#define MFMA16(A,B,C) __builtin_amdgcn_mfma_f32_16x16x32_f16(A,B,C,0,0,0)

// ---------- h[c] = 0.5*sum(e*e) with numpy pairwise-sum semantics (unchanged) ----------
__global__ void hsum_kernel(const float* __restrict__ books, float* __restrict__ hg) {
    int c = blockIdx.x * blockDim.x + threadIdx.x;
    if (c >= NB * NE) return;
    const float* e = books + (size_t)c * DDIM;
    float blk[2];
    for (int half = 0; half < 2; ++half) {
        const float* a = e + half * 128;
        float r[8];
        #pragma unroll
        for (int j = 0; j < 8; ++j) {
            float s = a[j] * a[j];
            asm volatile("" : "+v"(s));
            r[j] = s;
        }
        for (int i = 8; i < 128; i += 8) {
            #pragma unroll
            for (int j = 0; j < 8; ++j) {
                float s = a[i + j] * a[i + j];
                asm volatile("" : "+v"(s));
                r[j] = r[j] + s;
            }
        }
        blk[half] = ((r[0] + r[1]) + (r[2] + r[3])) + ((r[4] + r[5]) + (r[6] + r[7]));
    }
    hg[c] = 0.5f * (blk[0] + blk[1]);
}

// ---------- z (B,D,T) -> zt[token][dim] (unchanged) ----------
__global__ void txin_kernel(const float* __restrict__ z, float* __restrict__ zt) {
    __shared__ float ld[64 * 68];
    int t0 = blockIdx.x * 64, d0 = blockIdx.y * 64, b = blockIdx.z;
    int tid = threadIdx.x;
    {
        int dd = tid >> 2, t4 = (tid & 3) * 16;
        const float* zp = z + ((size_t)b * DDIM + d0 + dd) * TTOK + t0 + t4;
        #pragma unroll
        for (int c = 0; c < 16; c += 4)
            *(float4*)&ld[dd * 68 + t4 + c] = *(const float4*)(zp + c);
    }
    __syncthreads();
    {
        int t = tid >> 2, d4 = (tid & 3) * 16;
        float* rp = zt + ((size_t)b * TTOK + t0 + t) * DDIM + d0 + d4;
        #pragma unroll
        for (int c = 0; c < 16; c += 4) {
            float4 o;
            o.x = ld[(size_t)(d4 + c + 0) * 68 + t];
            o.y = ld[(size_t)(d4 + c + 1) * 68 + t];
            o.z = ld[(size_t)(d4 + c + 2) * 68 + t];
            o.w = ld[(size_t)(d4 + c + 3) * 68 + t];
            *(float4*)(rp + c) = o;
        }
    }
}

// ---------- books -> packed MFMA-B fragments: [b][F][s][{hi:512, lo:512}] ----------
// Fragment (b, F=nfrag 0..63, s=kstep 0..7): lane l, elem j holds
// code n = F*16 + (l&15), k = s*32 + (l>>4)*8 + j  (v_mfma_f32_16x16x32_f16 B layout).
// hi at +0, lo at +512 halves: one base address serves both loads (imm-offset pair),
// and the per-wave stream over (F, s) is a single linear walk (prefetch = p + 1024).
__global__ void bfrag_kernel(const float* __restrict__ books,
                             _Float16* __restrict__ Bp) {
    const int gid = blockIdx.x * 256 + threadIdx.x;   // 262144 total
    const int l = gid & 63;
    const int s = (gid >> 6) & 7;
    const int F = (gid >> 9) & 63;
    const int b = gid >> 15;
    const int n = F * 16 + (l & 15);
    const int k0 = s * 32 + (l >> 4) * 8;
    const float* src = books + ((size_t)b * NE + n) * DDIM + k0;
    float4 xa = *(const float4*)src;
    float4 xb = *(const float4*)(src + 4);
    float xs[8] = {xa.x, xa.y, xa.z, xa.w, xb.x, xb.y, xb.z, xb.w};
    half8 vh, vl;
    #pragma unroll
    for (int j = 0; j < 8; ++j) {
        float x = xs[j];
        _Float16 hx = (_Float16)x;
        float hf = (float)hx;
        // flush denormal hi at split time so MFMA's view == our compensated view
        if (__builtin_fabsf(hf) < 6.103515625e-05f) { hx = (_Float16)0.f; hf = 0.f; }
        vh[j] = hx;
        vl[j] = (_Float16)((x - hf) * 4096.f);   // x-hf exact (Sterbenz), *2^12 exact
    }
    const size_t o = (((size_t)b * 64 + F) * 8 + s) * 1024 + (size_t)l * 8;
    *(half8*)(Bp + o) = vh;
    *(half8*)(Bp + o + 512) = vl;
}

// ---------- main scan: split-fp16 MFMA scores + EPS-certified exact fallback ----------
// 512 threads = 8 waves; wave w scores all 64 tokens x codes [w*128, w*128+128).
// Register budget engineered for the RA's 128-VGPR bucket (R3 lesson: hints are
// ignored; overflow spills to scratch AND thrashes L3 for everyone):
//   v1/v2 32 + packed best-chunk 2 + acc 32 + B cur/prefetch 32 + A transient 16
//   + addressing ~8 (SGPR base via readfirstlane, rolling pointer) ~= 120.
__attribute__((amdgpu_flat_work_group_size(512, 512), amdgpu_waves_per_eu(1, 2)))
__global__ void vq_main(const float* __restrict__ books,
                        const _Float16* __restrict__ Bp,
                        const float* __restrict__ hg,
                        const float* __restrict__ zt,
                        int* __restrict__ idxg) {
    __shared__ float res_s[TM * RSTR];          // 66,560 B exact fp32 residual
    __shared__ _Float16 RHs[32 * 520];          // 33,280 B residual hi fragments
    __shared__ _Float16 RLs[32 * 520];          // 33,280 B residual lo fragments
    __shared__ float h_s[NE];                   // 4 KB per-book h
    __shared__ float cand_v1[8 * TM];
    __shared__ float cand_v2[8 * TM];
    __shared__ int   cand_n[8 * TM];
    __shared__ int   bidx_s[TM];
    __shared__ int   flist[TM];
    __shared__ int   nflag;

    const int tid  = threadIdx.x;
    const int lane = tid & 63;
    const int wu   = __builtin_amdgcn_readfirstlane(tid >> 6);  // wave id, SGPR
    const size_t tok0 = (size_t)blockIdx.x * TM;

    { // stage residual = z tokens into LDS
        int m = tid >> 3, qc = (tid & 7) * 32;
        const float* zp = zt + (tok0 + m) * DDIM + qc;
        float* rp = &res_s[m * RSTR + qc];
        #pragma unroll
        for (int c = 0; c < 32; c += 4)
            *(float4*)(rp + c) = *(const float4*)(zp + c);
    }

    const int fi = tid >> 4;       // fragment id 0..31 = m*8 + s
    const int fp = tid & 15;       // 1/16 of a fragment
    const int g  = lane >> 4;      // C-row group
    const int cl = lane & 15;      // C-col within fragment

    for (int b = 0; b < NB; ++b) {
        __syncthreads();           // res_s ready (initial stage or prev update)
        for (int i = tid; i < NE; i += 512) h_s[i] = hg[b * NE + i];
        if (tid == 0) nflag = 0;
        { // split residual -> fragment-ordered fp16 hi/lo (A layout: row=l&15, k=(l>>4)*8+j)
            const int sm = fi >> 3, ss = fi & 7;
            #pragma unroll
            for (int c = 0; c < 4; ++c) {
                int lp = fp * 4 + c;
                const float* rp = &res_s[(sm * 16 + (lp & 15)) * RSTR + ss * 32 + (lp >> 4) * 8];
                float4 xa = *(const float4*)rp;
                float4 xb = *(const float4*)(rp + 4);
                float xs[8] = {xa.x, xa.y, xa.z, xa.w, xb.x, xb.y, xb.z, xb.w};
                half8 vh, vl;
                #pragma unroll
                for (int j = 0; j < 8; ++j) {
                    float x = xs[j];
                    _Float16 hx = (_Float16)x;
                    float hf = (float)hx;
                    if (__builtin_fabsf(hf) < 6.103515625e-05f) { hx = (_Float16)0.f; hf = 0.f; }
                    vh[j] = hx;
                    vl[j] = (_Float16)((x - hf) * 4096.f);
                }
                *(half8*)&RHs[fi * 520 + fp * 32 + c * 8] = vh;
                *(half8*)&RLs[fi * 520 + fp * 32 + c * 8] = vl;
            }
        }
        __syncthreads();

        // per-lane running top-1 value + conservative second + packed best-chunk id
        // (slot sl = m*4 + r -> token m*16 + g*4 + r; code n = (wu*8+cc)*16 + cl)
        float v1[16], v2[16];
        unsigned bc0 = 0, bc1 = 0;       // 4-bit best-chunk per slot (slots 0-7 / 8-15)
        #pragma unroll
        for (int t = 0; t < 16; ++t) { v1[t] = -3.4e38f; v2[t] = -3.4e38f; }

        const f32x4 fz = {0.f, 0.f, 0.f, 0.f};
        // per-wave book stream: 8 frags x 8 steps x 2KB, perfectly linear
        const _Float16* p = Bp + (((size_t)(b * 64 + wu * 8)) << 13) + (size_t)(lane << 3);
        half8 bfh = *(const half8*)p;
        half8 bfl = *(const half8*)(p + 512);
        const _Float16* pn = p + 1024;   // rolling prefetch pointer

        for (int cc = 0; cc < 8; ++cc) {         // 8 chunks of 16 codes per wave
            f32x4 acch[4], accm[4];              // [mfrag]: hi*hi and mixed(x4096)
            #pragma unroll
            for (int m = 0; m < 4; ++m) { acch[m] = fz; accm[m] = fz; }

            #pragma unroll
            for (int s = 0; s < 8; ++s) {        // K = 8 * 32
                // prefetch next step (linear; one-past-end lands in zt, discarded)
                half8 qh = *(const half8*)pn;
                half8 ql = *(const half8*)(pn + 512);
                #pragma unroll
                for (int m = 0; m < 4; ++m) {
                    half8 ah = *(const half8*)&RHs[(m * 8 + s) * 520 + (lane << 3)];
                    acch[m] = MFMA16(ah, bfh, acch[m]);
                    accm[m] = MFMA16(ah, bfl, accm[m]);
                    half8 al = *(const half8*)&RLs[(m * 8 + s) * 520 + (lane << 3)];
                    accm[m] = MFMA16(al, bfh, accm[m]);
                }
                bfh = qh; bfl = ql; pn += 1024;
            }
            // score = dot - h; codes ascending (cc asc) -> strict '>' keeps first max
            const int n = (wu * 8 + cc) * 16 + cl;
            const float hv = h_s[n];
            #pragma unroll
            for (int m = 0; m < 4; ++m)
                #pragma unroll
                for (int r = 0; r < 4; ++r) {
                    float sc = acch[m][r] + 2.44140625e-4f * accm[m][r] - hv;
                    const int sl = m * 4 + r;
                    if (sc > v1[sl]) {
                        v2[sl] = v1[sl]; v1[sl] = sc;
                        if (sl < 8) bc0 = (bc0 & ~(15u << (4 * sl))) | ((unsigned)cc << (4 * sl));
                        else        bc1 = (bc1 & ~(15u << (4 * (sl - 8)))) | ((unsigned)cc << (4 * (sl - 8)));
                    } else v2[sl] = fmaxf(v2[sl], sc);
                }
        }
        // reconstruct best-code indices, then reduce top-2 across the 16 lanes
        int n1[16];
        #pragma unroll
        for (int sl = 0; sl < 16; ++sl) {
            unsigned bcc = (sl < 8) ? (bc0 >> (4 * sl)) : (bc1 >> (4 * (sl - 8)));
            n1[sl] = (wu * 8 + (int)(bcc & 15u)) * 16 + cl;
        }
        #pragma unroll
        for (int sl = 0; sl < 16; ++sl) {
            #pragma unroll
            for (int mk = 1; mk < 16; mk <<= 1) {
                float o1 = __shfl_xor(v1[sl], mk, 16);
                float o2 = __shfl_xor(v2[sl], mk, 16);
                int   on = __shfl_xor(n1[sl], mk, 16);
                if (o1 > v1[sl] || (o1 == v1[sl] && on < n1[sl])) {
                    v2[sl] = fmaxf(v1[sl], o2);
                    v1[sl] = o1; n1[sl] = on;
                } else {
                    v2[sl] = fmaxf(v2[sl], o1);
                }
            }
        }
        if (cl == 0) {
            #pragma unroll
            for (int sl = 0; sl < 16; ++sl) {
                int t = (sl >> 2) * 16 + g * 4 + (sl & 3);
                cand_v1[wu * TM + t] = v1[sl];
                cand_v2[wu * TM + t] = v2[sl];
                cand_n [wu * TM + t] = n1[sl];
            }
        }
        __syncthreads();
        // combine the 8 waves' candidates; flag near-ties for exact rescore
        if (tid < TM) {
            float b1v = cand_v1[tid], b2v = cand_v2[tid]; int bn = cand_n[tid];
            #pragma unroll
            for (int ww = 1; ww < 8; ++ww) {
                float o1 = cand_v1[ww * TM + tid], o2 = cand_v2[ww * TM + tid];
                int on = cand_n[ww * TM + tid];
                if (o1 > b1v) { b2v = fmaxf(b1v, o2); b1v = o1; bn = on; }
                else b2v = fmaxf(b2v, o1);   // ties (o1==b1v) drive gap to 0 -> flagged
            }
            bidx_s[tid] = bn;
            if (b1v - b2v < EPS_GAP) { int p2 = atomicAdd(&nflag, 1); flist[p2] = tid; }
        }
        __syncthreads();
        // exact fp32 rescore (validated numerics: k-ascending single-acc fmaf chain)
        {
            const int nfl = nflag;
            for (int f = wu; f < nfl; f += 8) {
                const int t = flist[f];
                const float* rrow = &res_s[t * RSTR];
                float best = -3.4e38f; int bestn = 0;
                for (int i = 0; i < 16; ++i) {
                    const int n = lane + (i << 6);
                    const float* crow = books + ((size_t)b * NE + n) * DDIM;
                    float acc = 0.f;
                    #pragma unroll 4
                    for (int k = 0; k < DDIM; k += 4) {
                        float4 rv = *(const float4*)(rrow + k);
                        float4 cv = *(const float4*)(crow + k);
                        acc = __builtin_fmaf(rv.x, cv.x, acc);
                        acc = __builtin_fmaf(rv.y, cv.y, acc);
                        acc = __builtin_fmaf(rv.z, cv.z, acc);
                        acc = __builtin_fmaf(rv.w, cv.w, acc);
                    }
                    float sc = acc - h_s[n];
                    if (sc > best) { best = sc; bestn = n; }
                }
                #pragma unroll
                for (int mk = 32; mk; mk >>= 1) {
                    float ov = __shfl_xor(best, mk, 64);
                    int   on = __shfl_xor(bestn, mk, 64);
                    if (ov > best || (ov == best && on < bestn)) { best = ov; bestn = on; }
                }
                if (lane == 0) bidx_s[t] = bestn;
            }
        }
        __syncthreads();
        if (tid < TM) idxg[(tok0 + tid) * NB + b] = bidx_s[tid];
        { // residual update r = r - q (plain fp32 subs, matches reference chain)
            int m = tid >> 3, qc = (tid & 7) * 32;
            const float* qrow = books + ((size_t)b * NE + bidx_s[m]) * DDIM + qc;
            float* rrow = &res_s[m * RSTR + qc];
            #pragma unroll
            for (int c2 = 0; c2 < 32; c2 += 4) {
                float4 qv = *(const float4*)(qrow + c2);
                float4 rv2 = *(float4*)(rrow + c2);
                rv2.x = rv2.x - qv.x; rv2.y = rv2.y - qv.y;
                rv2.z = rv2.z - qv.z; rv2.w = rv2.w - qv.w;
                *(float4*)(rrow + c2) = rv2;
            }
        }
    }
}

// ---------- replay: q_sum with the reference's exact fp32 op order (unchanged) ----------
__global__ void replay_kernel(const float* __restrict__ books,
                              const int* __restrict__ idxg,
                              float* __restrict__ zt) {
    size_t gid = (size_t)blockIdx.x * 256 + threadIdx.x;
    size_t tok = gid >> 6;
    int d4 = (int)(gid & 63) * 4;
    const int* ip = idxg + tok * NB;
    float4 r = *(const float4*)&zt[tok * DDIM + d4];
    float4 qs = make_float4(0.f, 0.f, 0.f, 0.f);
    #pragma unroll
    for (int b = 0; b < NB; ++b) {
        int idx = ip[b];
        float4 q = *(const float4*)&books[((size_t)b * NE + idx) * DDIM + d4];
        float t1;
        t1 = q.x - r.x; qs.x = qs.x + t1; qs.x = qs.x + r.x; r.x = r.x - q.x;
        t1 = q.y - r.y; qs.y = qs.y + t1; qs.y = qs.y + r.y; r.y = r.y - q.y;
        t1 = q.z - r.z; qs.z = qs.z + t1; qs.z = qs.z + r.z; r.z = r.z - q.z;
        t1 = q.w - r.w; qs.w = qs.w + t1; qs.w = qs.w + r.w; r.w = r.w - q.w;
    }
    *(float4*)&zt[tok * DDIM + d4] = qs;
}

// ---------- out (B,D,T) = transpose of q_sum[token][dim] (unchanged) ----------
__global__ void fin_kernel(const float* __restrict__ qst, float* __restrict__ out) {
    __shared__ float ld[64 * 68];
    int t0 = blockIdx.x * 64, d0 = blockIdx.y * 64, b = blockIdx.z;
    int tid = threadIdx.x;
    {
        int t = tid >> 2, d4 = (tid & 3) * 16;
        const float* rp = qst + ((size_t)b * TTOK + t0 + t) * DDIM + d0 + d4;
        #pragma unroll
        for (int c = 0; c < 16; c += 4)
            *(float4*)&ld[t * 68 + d4 + c] = *(const float4*)(rp + c);
    }
    __syncthreads();
    {
        int dd = tid >> 2, t4 = (tid & 3) * 16;
        float* op = out + ((size_t)b * DDIM + d0 + dd) * TTOK + t0 + t4;
        #pragma unroll
        for (int c = 0; c < 16; c += 4) {
            float4 o;
            o.x = ld[(size_t)(t4 + c + 0) * 68 + dd];
            o.y = ld[(size_t)(t4 + c + 1) * 68 + dd];
            o.z = ld[(size_t)(t4 + c + 2) * 68 + dd];
            o.w = ld[(size_t)(t4 + c + 3) * 68 + dd];
            *(float4*)(op + c) = o;
        }
    }
}

extern "C" void kernel_launch(void* const* d_in, const int* in_sizes, int n_in,
                              void* d_out, int out_size, void* d_ws, size_t ws_size,
                              hipStream_t stream) {
    const float* z     = (const float*)d_in[0];
    const float* books = (const float*)d_in[1];
    float* out = (float*)d_out;

    float* hg    = (float*)d_ws;                         // 8192 floats
    int*   idxg  = (int*)(hg + (size_t)NB * NE);         // 65536*8 ints (2 MB)
    _Float16* Bp = (_Float16*)(idxg + (size_t)NTOK * NB);// 8 MB packed hi/lo fragments
    float* zt    = (float*)(Bp + (size_t)NB * NE * DDIM * 2); // 64 MB token-major
    // NOTE: vq_main's rolling prefetch reads 2KB past Bp's end -> lands in zt, discarded.

    hsum_kernel<<<(NB * NE + 255) / 256, 256, 0, stream>>>(books, hg);
    bfrag_kernel<<<(NB * 64 * 8 * 64) / 256, 256, 0, stream>>>(books, Bp);
    txin_kernel<<<dim3(TTOK / 64, DDIM / 64, BBATCH), 256, 0, stream>>>(z, zt);
    vq_main<<<NTOK / TM, 512, 0, stream>>>(books, Bp, hg, zt, idxg);
    replay_kernel<<<NTOK * 64 / 256, 256, 0, stream>>>(books, idxg, zt);
    fin_kernel<<<dim3(TTOK / 64, DDIM / 64, BBATCH), 256, 0, stream>>>(zt, out);
}

// Round 5
// 1802.054 us; speedup vs baseline: 2.4784x; 2.4784x over previous
//
#include <hip/hip_runtime.h>
#include <math.h>

#define NB    8
#define NE    1024
#define DDIM  256
#define TTOK  4096
#define BBATCH 16
#define NTOK  (BBATCH*TTOK)   // 65536

#define TM    64      // tokens per block
#define RSTR  260     // res_s row stride (floats), 16B aligned
#define EPS_GAP 1e-4f // certify threshold: approx top-2 gap below this -> exact rescore

typedef _Float16 half8 __attribute__((ext_vector_type(8)));
typedef float f32x4 __attribute__((ext_vector_type(4)));

#define MFMA16(A,B,C) __builtin_amdgcn_mfma_f32_16x16x32_f16(A,B,C,0,0,0)

// ---------- h[c] = 0.5*sum(e*e) with numpy pairwise-sum semantics (unchanged) ----------
__global__ void hsum_kernel(const float* __restrict__ books, float* __restrict__ hg) {
    int c = blockIdx.x * blockDim.x + threadIdx.x;
    if (c >= NB * NE) return;
    const float* e = books + (size_t)c * DDIM;
    float blk[2];
    for (int half = 0; half < 2; ++half) {
        const float* a = e + half * 128;
        float r[8];
        #pragma unroll
        for (int j = 0; j < 8; ++j) {
            float s = a[j] * a[j];
            asm volatile("" : "+v"(s));
            r[j] = s;
        }
        for (int i = 8; i < 128; i += 8) {
            #pragma unroll
            for (int j = 0; j < 8; ++j) {
                float s = a[i + j] * a[i + j];
                asm volatile("" : "+v"(s));
                r[j] = r[j] + s;
            }
        }
        blk[half] = ((r[0] + r[1]) + (r[2] + r[3])) + ((r[4] + r[5]) + (r[6] + r[7]));
    }
    hg[c] = 0.5f * (blk[0] + blk[1]);
}

// ---------- z (B,D,T) -> zt[token][dim] (unchanged) ----------
__global__ void txin_kernel(const float* __restrict__ z, float* __restrict__ zt) {
    __shared__ float ld[64 * 68];
    int t0 = blockIdx.x * 64, d0 = blockIdx.y * 64, b = blockIdx.z;
    int tid = threadIdx.x;
    {
        int dd = tid >> 2, t4 = (tid & 3) * 16;
        const float* zp = z + ((size_t)b * DDIM + d0 + dd) * TTOK + t0 + t4;
        #pragma unroll
        for (int c = 0; c < 16; c += 4)
            *(float4*)&ld[dd * 68 + t4 + c] = *(const float4*)(zp + c);
    }
    __syncthreads();
    {
        int t = tid >> 2, d4 = (tid & 3) * 16;
        float* rp = zt + ((size_t)b * TTOK + t0 + t) * DDIM + d0 + d4;
        #pragma unroll
        for (int c = 0; c < 16; c += 4) {
            float4 o;
            o.x = ld[(size_t)(d4 + c + 0) * 68 + t];
            o.y = ld[(size_t)(d4 + c + 1) * 68 + t];
            o.z = ld[(size_t)(d4 + c + 2) * 68 + t];
            o.w = ld[(size_t)(d4 + c + 3) * 68 + t];
            *(float4*)(rp + c) = o;
        }
    }
}

// ---------- books -> stream-ordered packed MFMA-B fragments ----------
// Layout: [ch 2][b 8][cc 16][s 8] packets of 4KB; packet = {f0 hi 1KB, f0 lo 1KB,
// f1 hi 1KB, f1 lo 1KB} where f0/f1 are code-frags F = ch*32 + cc*2 + {0,1}.
// Within a 1KB piece: lane l elem j holds code n = F*16 + (l&15),
// k = s*32 + (l>>4)*8 + j (v_mfma_f32_16x16x32_f16 B layout).
// Per code-half the walk over (b, cc, s) is ONE linear 4MB stream.
__global__ void bfrag_kernel(const float* __restrict__ books,
                             _Float16* __restrict__ Bp) {
    const int gid = blockIdx.x * 256 + threadIdx.x;   // 262144 total
    const int l = gid & 63;
    const int s = (gid >> 6) & 7;
    const int F = (gid >> 9) & 63;
    const int b = gid >> 15;
    const int ch = F >> 5, cc = (F >> 1) & 15, pr = F & 1;
    const int n = F * 16 + (l & 15);
    const int k0 = s * 32 + (l >> 4) * 8;
    const float* src = books + ((size_t)b * NE + n) * DDIM + k0;
    float4 xa = *(const float4*)src;
    float4 xb = *(const float4*)(src + 4);
    float xs[8] = {xa.x, xa.y, xa.z, xa.w, xb.x, xb.y, xb.z, xb.w};
    half8 vh, vl;
    #pragma unroll
    for (int j = 0; j < 8; ++j) {
        float x = xs[j];
        _Float16 hx = (_Float16)x;
        float hf = (float)hx;
        // flush denormal hi at split time so MFMA's view == our compensated view
        if (__builtin_fabsf(hf) < 6.103515625e-05f) { hx = (_Float16)0.f; hf = 0.f; }
        vh[j] = hx;
        vl[j] = (_Float16)((x - hf) * 4096.f);   // x-hf exact (Sterbenz), *2^12 exact
    }
    const size_t pkt = (((size_t)ch * 8 + b) * 16 + cc) * 8 + s;
    const size_t o = pkt * 2048 + (size_t)pr * 1024 + (size_t)l * 8;
    *(half8*)(Bp + o) = vh;
    *(half8*)(Bp + o + 512) = vl;
}

// ---------- main scan: split-fp16 MFMA scores + EPS-certified exact fallback ----------
// 512 threads = 8 waves. Wave w owns m-frag mf=w&3 (16 tokens) and code-half
// ch=w>>2 (512 codes). R4 lesson: fully-unrolled chunk loops let the scheduler
// hoist 16 B-loads (64 VGPRs) -> spill at the RA's 128 bucket. Here the B data
// lives in an EXPLICIT 4-deep rolling register queue (64 VGPRs) over a linear
// 4MB/ch stream; sched_barrier(0) per k-step pins refills to their step so the
// window never exceeds 4 packets. Top-2 state is 9 regs (v1[4],v2[4],packed bc).
// Audit: 64 q + 16 acc + 9 top2 + 16 A cur/next + ~18 addr/misc ~= 123 < 128.
__launch_bounds__(512)
__global__ void vq_main(const float* __restrict__ books,
                        const _Float16* __restrict__ Bp,
                        const float* __restrict__ hg,
                        const float* __restrict__ zt,
                        int* __restrict__ idxg) {
    __shared__ float res_s[TM * RSTR];          // 66,560 B exact fp32 residual
    __shared__ _Float16 RHs[32 * 520];          // 33,280 B residual hi fragments
    __shared__ _Float16 RLs[32 * 520];          // 33,280 B residual lo fragments
    __shared__ float h_s[NE];                   // 4 KB per-book h
    __shared__ float cand_v1[2 * TM];
    __shared__ float cand_v2[2 * TM];
    __shared__ int   cand_n[2 * TM];
    __shared__ int   bidx_s[TM];
    __shared__ int   flist[TM];
    __shared__ int   nflag;

    const int tid  = threadIdx.x;
    const int lane = tid & 63;
    const int w    = tid >> 6;
    const int mf   = w & 3;        // token m-frag (tokens mf*16..mf*16+15)
    const int ch   = w >> 2;       // code half (codes ch*512..ch*512+511)
    const int g    = lane >> 4;    // C-row group
    const int cl   = lane & 15;    // C-col within fragment
    const size_t tok0 = (size_t)blockIdx.x * TM;

    { // stage residual = z tokens into LDS
        int m = tid >> 3, qc = (tid & 7) * 32;
        const float* zp = zt + (tok0 + m) * DDIM + qc;
        float* rp = &res_s[m * RSTR + qc];
        #pragma unroll
        for (int c = 0; c < 32; c += 4)
            *(float4*)(rp + c) = *(const float4*)(zp + c);
    }

    // ---- B stream: prologue-fill the 4-deep queue (rolls across books) ----
    const _Float16* sp = Bp + ((size_t)ch << 21) + (size_t)(lane << 3);
    half8 qf0h[4], qf0l[4], qf1h[4], qf1l[4];
    #pragma unroll
    for (int i = 0; i < 4; ++i) {
        qf0h[i] = *(const half8*)(sp + 0);
        qf0l[i] = *(const half8*)(sp + 512);
        qf1h[i] = *(const half8*)(sp + 1024);
        qf1l[i] = *(const half8*)(sp + 1536);
        sp += 2048;
    }

    const int fi = tid >> 4;       // fragment id 0..31 = m*8 + s (split phase)
    const int fp = tid & 15;       // 1/16 of a fragment
    const int abase = mf * 8;      // this wave's RHs/RLs fragment base

    for (int b = 0; b < NB; ++b) {
        __syncthreads();           // res_s ready (initial stage or prev update)
        for (int i = tid; i < NE; i += 512) h_s[i] = hg[b * NE + i];
        if (tid == 0) nflag = 0;
        { // split residual -> fragment-ordered fp16 hi/lo (A layout: row=l&15, k=(l>>4)*8+j)
            const int sm = fi >> 3, ss = fi & 7;
            #pragma unroll
            for (int c = 0; c < 4; ++c) {
                int lp = fp * 4 + c;
                const float* rp = &res_s[(sm * 16 + (lp & 15)) * RSTR + ss * 32 + (lp >> 4) * 8];
                float4 xa = *(const float4*)rp;
                float4 xb = *(const float4*)(rp + 4);
                float xs[8] = {xa.x, xa.y, xa.z, xa.w, xb.x, xb.y, xb.z, xb.w};
                half8 vh, vl;
                #pragma unroll
                for (int j = 0; j < 8; ++j) {
                    float x = xs[j];
                    _Float16 hx = (_Float16)x;
                    float hf = (float)hx;
                    if (__builtin_fabsf(hf) < 6.103515625e-05f) { hx = (_Float16)0.f; hf = 0.f; }
                    vh[j] = hx;
                    vl[j] = (_Float16)((x - hf) * 4096.f);
                }
                *(half8*)&RHs[fi * 520 + fp * 32 + c * 8] = vh;
                *(half8*)&RLs[fi * 520 + fp * 32 + c * 8] = vl;
            }
        }
        __syncthreads();

        // per-lane running top-2 for 4 token slots (slot r -> token mf*16 + g*4 + r)
        float v1[4], v2[4];
        unsigned bc = 0;           // 5-bit best local-frag index per slot
        #pragma unroll
        for (int r = 0; r < 4; ++r) { v1[r] = -3.4e38f; v2[r] = -3.4e38f; }

        // A prologue for s=0 of this book
        half8 ahc = *(const half8*)&RHs[abase * 520 + (lane << 3)];
        half8 alc = *(const half8*)&RLs[abase * 520 + (lane << 3)];

        const f32x4 fz = {0.f, 0.f, 0.f, 0.f};
        for (int cc = 0; cc < 16; ++cc) {        // 16 chunks of 2 frags (32 codes)
            f32x4 acch[2], accm[2];              // [frag]: hi*hi and mixed(x4096)
            acch[0] = fz; acch[1] = fz; accm[0] = fz; accm[1] = fz;

            #pragma unroll
            for (int s = 0; s < 8; ++s) {        // K = 8 * 32
                const int sq = s & 3;            // queue slot (static)
                const int sn = (s + 1) & 7;      // next A step (wraps; same values)
                half8 ahn = *(const half8*)&RHs[(abase + sn) * 520 + (lane << 3)];
                half8 aln = *(const half8*)&RLs[(abase + sn) * 520 + (lane << 3)];
                // validated chain order per acc: ah*bh ; ah*bl ; al*bh
                acch[0] = MFMA16(ahc, qf0h[sq], acch[0]);
                accm[0] = MFMA16(ahc, qf0l[sq], accm[0]);
                accm[0] = MFMA16(alc, qf0h[sq], accm[0]);
                acch[1] = MFMA16(ahc, qf1h[sq], acch[1]);
                accm[1] = MFMA16(ahc, qf1l[sq], accm[1]);
                accm[1] = MFMA16(alc, qf1h[sq], accm[1]);
                // refill this slot with packet t+4 (linear; overrun past Bp -> zt, discarded)
                qf0h[sq] = *(const half8*)(sp + 0);
                qf0l[sq] = *(const half8*)(sp + 512);
                qf1h[sq] = *(const half8*)(sp + 1024);
                qf1l[sq] = *(const half8*)(sp + 1536);
                sp += 2048;
                ahc = ahn; alc = aln;
                __builtin_amdgcn_sched_barrier(0);   // pin the 4-deep window
            }
            // fold: codes ascending (cc asc, f asc) -> strict '>' keeps first max
            #pragma unroll
            for (int f = 0; f < 2; ++f) {
                const int n = ((ch * 32 + cc * 2 + f) << 4) + cl;
                const float hv = h_s[n];
                #pragma unroll
                for (int r = 0; r < 4; ++r) {
                    float sc = acch[f][r] + 2.44140625e-4f * accm[f][r] - hv;
                    if (sc > v1[r]) {
                        v2[r] = v1[r]; v1[r] = sc;
                        bc = (bc & ~(31u << (5 * r))) | ((unsigned)(cc * 2 + f) << (5 * r));
                    } else v2[r] = fmaxf(v2[r], sc);
                }
            }
        }
        // reconstruct best-code indices, then reduce top-2 across the 16 lanes
        int n1[4];
        #pragma unroll
        for (int r = 0; r < 4; ++r)
            n1[r] = ((ch * 32 + (int)((bc >> (5 * r)) & 31u)) << 4) + cl;
        #pragma unroll
        for (int r = 0; r < 4; ++r) {
            #pragma unroll
            for (int mk = 1; mk < 16; mk <<= 1) {
                float o1 = __shfl_xor(v1[r], mk, 16);
                float o2 = __shfl_xor(v2[r], mk, 16);
                int   on = __shfl_xor(n1[r], mk, 16);
                if (o1 > v1[r] || (o1 == v1[r] && on < n1[r])) {
                    v2[r] = fmaxf(v1[r], o2);
                    v1[r] = o1; n1[r] = on;
                } else {
                    v2[r] = fmaxf(v2[r], o1);
                }
            }
        }
        if (cl == 0) {
            #pragma unroll
            for (int r = 0; r < 4; ++r) {
                int t = mf * 16 + g * 4 + r;
                cand_v1[ch * TM + t] = v1[r];
                cand_v2[ch * TM + t] = v2[r];
                cand_n [ch * TM + t] = n1[r];
            }
        }
        __syncthreads();
        // combine the two code-halves; flag near-ties for exact rescore
        if (tid < TM) {
            float b1v = cand_v1[tid], b2v = cand_v2[tid]; int bn = cand_n[tid];
            float o1 = cand_v1[TM + tid], o2 = cand_v2[TM + tid];
            int   on = cand_n[TM + tid];
            if (o1 > b1v) { b2v = fmaxf(b1v, o2); b1v = o1; bn = on; }
            else b2v = fmaxf(b2v, o1);   // ties (o1==b1v) drive gap to 0 -> flagged
            bidx_s[tid] = bn;
            if (b1v - b2v < EPS_GAP) { int p2 = atomicAdd(&nflag, 1); flist[p2] = tid; }
        }
        __syncthreads();
        // exact fp32 rescore (validated numerics: k-ascending single-acc fmaf chain)
        {
            const int nfl = nflag;
            for (int f = w; f < nfl; f += 8) {
                const int t = flist[f];
                const float* rrow = &res_s[t * RSTR];
                float best = -3.4e38f; int bestn = 0;
                for (int i = 0; i < 16; ++i) {
                    const int n = lane + (i << 6);
                    const float* crow = books + ((size_t)b * NE + n) * DDIM;
                    float acc = 0.f;
                    #pragma unroll 4
                    for (int k = 0; k < DDIM; k += 4) {
                        float4 rv = *(const float4*)(rrow + k);
                        float4 cv = *(const float4*)(crow + k);
                        acc = __builtin_fmaf(rv.x, cv.x, acc);
                        acc = __builtin_fmaf(rv.y, cv.y, acc);
                        acc = __builtin_fmaf(rv.z, cv.z, acc);
                        acc = __builtin_fmaf(rv.w, cv.w, acc);
                    }
                    float sc = acc - h_s[n];
                    if (sc > best) { best = sc; bestn = n; }
                }
                #pragma unroll
                for (int mk = 32; mk; mk >>= 1) {
                    float ov = __shfl_xor(best, mk, 64);
                    int   on = __shfl_xor(bestn, mk, 64);
                    if (ov > best || (ov == best && on < bestn)) { best = ov; bestn = on; }
                }
                if (lane == 0) bidx_s[t] = bestn;
            }
        }
        __syncthreads();
        if (tid < TM) idxg[(tok0 + tid) * NB + b] = bidx_s[tid];
        { // residual update r = r - q (plain fp32 subs, matches reference chain)
            int m = tid >> 3, qc = (tid & 7) * 32;
            const float* qrow = books + ((size_t)b * NE + bidx_s[m]) * DDIM + qc;
            float* rrow = &res_s[m * RSTR + qc];
            #pragma unroll
            for (int c2 = 0; c2 < 32; c2 += 4) {
                float4 qv = *(const float4*)(qrow + c2);
                float4 rv2 = *(float4*)(rrow + c2);
                rv2.x = rv2.x - qv.x; rv2.y = rv2.y - qv.y;
                rv2.z = rv2.z - qv.z; rv2.w = rv2.w - qv.w;
                *(float4*)(rrow + c2) = rv2;
            }
        }
    }
}

// ---------- replay: q_sum with the reference's exact fp32 op order (unchanged) ----------
__global__ void replay_kernel(const float* __restrict__ books,
                              const int* __restrict__ idxg,
                              float* __restrict__ zt) {
    size_t gid = (size_t)blockIdx.x * 256 + threadIdx.x;
    size_t tok = gid >> 6;
    int d4 = (int)(gid & 63) * 4;
    const int* ip = idxg + tok * NB;
    float4 r = *(const float4*)&zt[tok * DDIM + d4];
    float4 qs = make_float4(0.f, 0.f, 0.f, 0.f);
    #pragma unroll
    for (int b = 0; b < NB; ++b) {
        int idx = ip[b];
        float4 q = *(const float4*)&books[((size_t)b * NE + idx) * DDIM + d4];
        float t1;
        t1 = q.x - r.x; qs.x = qs.x + t1; qs.x = qs.x + r.x; r.x = r.x - q.x;
        t1 = q.y - r.y; qs.y = qs.y + t1; qs.y = qs.y + r.y; r.y = r.y - q.y;
        t1 = q.z - r.z; qs.z = qs.z + t1; qs.z = qs.z + r.z; r.z = r.z - q.z;
        t1 = q.w - r.w; qs.w = qs.w + t1; qs.w = qs.w + r.w; r.w = r.w - q.w;
    }
    *(float4*)&zt[tok * DDIM + d4] = qs;
}

// ---------- out (B,D,T) = transpose of q_sum[token][dim] (unchanged) ----------
__global__ void fin_kernel(const float* __restrict__ qst, float* __restrict__ out) {
    __shared__ float ld[64 * 68];
    int t0 = blockIdx.x * 64, d0 = blockIdx.y * 64, b = blockIdx.z;
    int tid = threadIdx.x;
    {
        int t = tid >> 2, d4 = (tid & 3) * 16;
        const float* rp = qst + ((size_t)b * TTOK + t0 + t) * DDIM + d0 + d4;
        #pragma unroll
        for (int c = 0; c < 16; c += 4)
            *(float4*)&ld[t * 68 + d4 + c] = *(const float4*)(rp + c);
    }
    __syncthreads();
    {
        int dd = tid >> 2, t4 = (tid & 3) * 16;
        float* op = out + ((size_t)b * DDIM + d0 + dd) * TTOK + t0 + t4;
        #pragma unroll
        for (int c = 0; c < 16; c += 4) {
            float4 o;
            o.x = ld[(size_t)(t4 + c + 0) * 68 + dd];
            o.y = ld[(size_t)(t4 + c + 1) * 68 + dd];
            o.z = ld[(size_t)(t4 + c + 2) * 68 + dd];
            o.w = ld[(size_t)(t4 + c + 3) * 68 + dd];
            *(float4*)(op + c) = o;
        }
    }
}

extern "C" void kernel_launch(void* const* d_in, const int* in_sizes, int n_in,
                              void* d_out, int out_size, void* d_ws, size_t ws_size,
                              hipStream_t stream) {
    const float* z     = (const float*)d_in[0];
    const float* books = (const float*)d_in[1];
    float* out = (float*)d_out;

    float* hg    = (float*)d_ws;                         // 8192 floats
    int*   idxg  = (int*)(hg + (size_t)NB * NE);         // 65536*8 ints (2 MB)
    _Float16* Bp = (_Float16*)(idxg + (size_t)NTOK * NB);// 8 MB stream-ordered fragments
    float* zt    = (float*)(Bp + (size_t)NB * NE * DDIM * 2); // 64 MB token-major
    // NOTE: vq_main's rolling 4-deep prefetch reads <=16KB past Bp's end -> zt, discarded.

    hsum_kernel<<<(NB * NE + 255) / 256, 256, 0, stream>>>(books, hg);
    bfrag_kernel<<<(NB * 64 * 8 * 64) / 256, 256, 0, stream>>>(books, Bp);
    txin_kernel<<<dim3(TTOK / 64, DDIM / 64, BBATCH), 256, 0, stream>>>(z, zt);
    vq_main<<<NTOK / TM, 512, 0, stream>>>(books, Bp, hg, zt, idxg);
    replay_kernel<<<NTOK * 64 / 256, 256, 0, stream>>>(books, idxg, zt);
    fin_kernel<<<dim3(TTOK / 64, DDIM / 64, BBATCH), 256, 0, stream>>>(zt, out);
}

// Round 6
// 1648.478 us; speedup vs baseline: 2.7093x; 1.0932x over previous
//
#include <hip/hip_runtime.h>
#include <math.h>

#define NB    8
#define NE    1024
#define DDIM  256
#define TTOK  4096
#define BBATCH 16
#define NTOK  (BBATCH*TTOK)   // 65536

#define TM    64      // tokens per block
#define RSTR  260     // res_s row stride (floats), 16B aligned
#define EPS_GAP 1e-4f // certify threshold: approx top-2 gap below this -> exact rescore

typedef _Float16 half8 __attribute__((ext_vector_type(8)));
typedef float f32x4 __attribute__((ext_vector_type(4)));

#define MFMA16(A,B,C) __builtin_amdgcn_mfma_f32_16x16x32_f16(A,B,C,0,0,0)

// ---------- h[c] = 0.5*sum(e*e) with numpy pairwise-sum semantics (unchanged) ----------
__global__ void hsum_kernel(const float* __restrict__ books, float* __restrict__ hg) {
    int c = blockIdx.x * blockDim.x + threadIdx.x;
    if (c >= NB * NE) return;
    const float* e = books + (size_t)c * DDIM;
    float blk[2];
    for (int half = 0; half < 2; ++half) {
        const float* a = e + half * 128;
        float r[8];
        #pragma unroll
        for (int j = 0; j < 8; ++j) {
            float s = a[j] * a[j];
            asm volatile("" : "+v"(s));
            r[j] = s;
        }
        for (int i = 8; i < 128; i += 8) {
            #pragma unroll
            for (int j = 0; j < 8; ++j) {
                float s = a[i + j] * a[i + j];
                asm volatile("" : "+v"(s));
                r[j] = r[j] + s;
            }
        }
        blk[half] = ((r[0] + r[1]) + (r[2] + r[3])) + ((r[4] + r[5]) + (r[6] + r[7]));
    }
    hg[c] = 0.5f * (blk[0] + blk[1]);
}

// ---------- z (B,D,T) -> zt[token][dim] (unchanged) ----------
__global__ void txin_kernel(const float* __restrict__ z, float* __restrict__ zt) {
    __shared__ float ld[64 * 68];
    int t0 = blockIdx.x * 64, d0 = blockIdx.y * 64, b = blockIdx.z;
    int tid = threadIdx.x;
    {
        int dd = tid >> 2, t4 = (tid & 3) * 16;
        const float* zp = z + ((size_t)b * DDIM + d0 + dd) * TTOK + t0 + t4;
        #pragma unroll
        for (int c = 0; c < 16; c += 4)
            *(float4*)&ld[dd * 68 + t4 + c] = *(const float4*)(zp + c);
    }
    __syncthreads();
    {
        int t = tid >> 2, d4 = (tid & 3) * 16;
        float* rp = zt + ((size_t)b * TTOK + t0 + t) * DDIM + d0 + d4;
        #pragma unroll
        for (int c = 0; c < 16; c += 4) {
            float4 o;
            o.x = ld[(size_t)(d4 + c + 0) * 68 + t];
            o.y = ld[(size_t)(d4 + c + 1) * 68 + t];
            o.z = ld[(size_t)(d4 + c + 2) * 68 + t];
            o.w = ld[(size_t)(d4 + c + 3) * 68 + t];
            *(float4*)(rp + c) = o;
        }
    }
}

// ---------- books -> stream-ordered packed MFMA-B fragments ----------
// Layout: [cq 4][b 8][cc 8][s 8] packets of 4KB; packet = {f0 hi 1KB, f0 lo 1KB,
// f1 hi 1KB, f1 lo 1KB} where f0/f1 = code-frags F = cq*16 + cc*2 + {0,1}.
// Within a 1KB piece: lane l elem j holds code n = F*16 + (l&15),
// k = s*32 + (l>>4)*8 + j (v_mfma_f32_16x16x32_f16 B layout).
// Per code-quarter the walk over (b, cc, s) is ONE linear 2MB stream.
__global__ void bfrag_kernel(const float* __restrict__ books,
                             _Float16* __restrict__ Bp) {
    const int gid = blockIdx.x * 256 + threadIdx.x;   // 262144 total
    const int l = gid & 63;
    const int s = (gid >> 6) & 7;
    const int F = (gid >> 9) & 63;
    const int b = gid >> 15;
    const int cq = F >> 4, cc = (F >> 1) & 7, pr = F & 1;
    const int n = F * 16 + (l & 15);
    const int k0 = s * 32 + (l >> 4) * 8;
    const float* src = books + ((size_t)b * NE + n) * DDIM + k0;
    float4 xa = *(const float4*)src;
    float4 xb = *(const float4*)(src + 4);
    float xs[8] = {xa.x, xa.y, xa.z, xa.w, xb.x, xb.y, xb.z, xb.w};
    half8 vh, vl;
    #pragma unroll
    for (int j = 0; j < 8; ++j) {
        float x = xs[j];
        _Float16 hx = (_Float16)x;
        float hf = (float)hx;
        // flush denormal hi at split time so MFMA's view == our compensated view
        if (__builtin_fabsf(hf) < 6.103515625e-05f) { hx = (_Float16)0.f; hf = 0.f; }
        vh[j] = hx;
        vl[j] = (_Float16)((x - hf) * 4096.f);   // x-hf exact (Sterbenz), *2^12 exact
    }
    const size_t pkt = (((size_t)cq * 8 + b) * 8 + cc) * 8 + s;
    const size_t o = pkt * 2048 + (size_t)pr * 1024 + (size_t)l * 8;
    *(half8*)(Bp + o) = vh;
    *(half8*)(Bp + o + 512) = vl;
}

// ---------- main scan: split-fp16 MFMA scores + EPS-certified exact fallback ----------
// 512 threads = 8 waves. Wave w owns token-half th=w&1 (32 tokens, m-frags 2th/2th+1)
// and code-quarter cq=w>>1 (256 codes). R5 lesson (VMEM-bound): 4 waves sharing a
// code stream = 4x duplicated load issue; 2x2 decomposition halves B-load instrs
// AND doubles MFMA per step (12). B lives in an explicit 2-deep rolling register
// queue (32 VGPRs) over a linear 2MB/cq stream; sched_barrier(0) per k-step pins
// the window (R5-proven: this is what keeps the RA honest at <128 VGPRs).
// Audit: 32 q + 32 acc + 16 A transient + 16 v1/v2 + 1 bc + ~14 addr ~= 111.
__launch_bounds__(512)
__global__ void vq_main(const float* __restrict__ books,
                        const _Float16* __restrict__ Bp,
                        const float* __restrict__ hg,
                        const float* __restrict__ zt,
                        int* __restrict__ idxg) {
    __shared__ float res_s[TM * RSTR];          // 66,560 B exact fp32 residual
    __shared__ _Float16 RHs[32 * 520];          // 33,280 B residual hi fragments
    __shared__ _Float16 RLs[32 * 520];          // 33,280 B residual lo fragments
    __shared__ float h_s[NE];                   // 4 KB per-book h
    __shared__ float cand_v1[4 * TM];
    __shared__ float cand_v2[4 * TM];
    __shared__ int   cand_n[4 * TM];
    __shared__ int   bidx_s[TM];
    __shared__ int   flist[TM];
    __shared__ int   nflag;

    const int tid  = threadIdx.x;
    const int lane = tid & 63;
    const int w    = tid >> 6;
    const int th   = w & 1;        // token half (m-frags 2th, 2th+1)
    const int cq   = w >> 1;       // code quarter (codes cq*256..cq*256+255)
    const int g    = lane >> 4;    // C-row group
    const int cl   = lane & 15;    // C-col within fragment
    const size_t tok0 = (size_t)blockIdx.x * TM;

    { // stage residual = z tokens into LDS
        int m = tid >> 3, qc = (tid & 7) * 32;
        const float* zp = zt + (tok0 + m) * DDIM + qc;
        float* rp = &res_s[m * RSTR + qc];
        #pragma unroll
        for (int c = 0; c < 32; c += 4)
            *(float4*)(rp + c) = *(const float4*)(zp + c);
    }

    // ---- B stream: prologue-fill the 2-deep packet queue (rolls across books) ----
    const _Float16* sp = Bp + ((size_t)cq << 20) + (size_t)(lane << 3);
    half8 q0h[2], q0l[2], q1h[2], q1l[2];
    #pragma unroll
    for (int i = 0; i < 2; ++i) {
        q0h[i] = *(const half8*)(sp + 0);
        q0l[i] = *(const half8*)(sp + 512);
        q1h[i] = *(const half8*)(sp + 1024);
        q1l[i] = *(const half8*)(sp + 1536);
        sp += 2048;
    }

    const int fi = tid >> 4;       // fragment id 0..31 = m*8 + s (split phase)
    const int fp = tid & 15;       // 1/16 of a fragment
    const int a0 = (th * 2) * 8;   // m-frag 0 row base in RHs/RLs
    const int a1 = (th * 2 + 1) * 8;

    for (int b = 0; b < NB; ++b) {
        __syncthreads();           // res_s ready (initial stage or prev update)
        for (int i = tid; i < NE; i += 512) h_s[i] = hg[b * NE + i];
        if (tid == 0) nflag = 0;
        { // split residual -> fragment-ordered fp16 hi/lo (A layout: row=l&15, k=(l>>4)*8+j)
            const int sm = fi >> 3, ss = fi & 7;
            #pragma unroll
            for (int c = 0; c < 4; ++c) {
                int lp = fp * 4 + c;
                const float* rp = &res_s[(sm * 16 + (lp & 15)) * RSTR + ss * 32 + (lp >> 4) * 8];
                float4 xa = *(const float4*)rp;
                float4 xb = *(const float4*)(rp + 4);
                float xs[8] = {xa.x, xa.y, xa.z, xa.w, xb.x, xb.y, xb.z, xb.w};
                half8 vh, vl;
                #pragma unroll
                for (int j = 0; j < 8; ++j) {
                    float x = xs[j];
                    _Float16 hx = (_Float16)x;
                    float hf = (float)hx;
                    if (__builtin_fabsf(hf) < 6.103515625e-05f) { hx = (_Float16)0.f; hf = 0.f; }
                    vh[j] = hx;
                    vl[j] = (_Float16)((x - hf) * 4096.f);
                }
                *(half8*)&RHs[fi * 520 + fp * 32 + c * 8] = vh;
                *(half8*)&RLs[fi * 520 + fp * 32 + c * 8] = vl;
            }
        }
        __syncthreads();

        // per-lane running top-2 for 8 token slots (slot mfl*4+r -> token th*32+mfl*16+g*4+r)
        float v1[8], v2[8];
        unsigned bc = 0;           // 4-bit best chunk-frag (cc*2+f) per slot
        #pragma unroll
        for (int r = 0; r < 8; ++r) { v1[r] = -3.4e38f; v2[r] = -3.4e38f; }

        const f32x4 fz = {0.f, 0.f, 0.f, 0.f};
        for (int cc = 0; cc < 8; ++cc) {         // 8 chunks of 2 frags (32 codes)
            f32x4 acch[4], accm[4];              // [f*2+mfl]: hi*hi and mixed(x4096)
            #pragma unroll
            for (int m = 0; m < 4; ++m) { acch[m] = fz; accm[m] = fz; }

            #pragma unroll
            for (int s = 0; s < 8; ++s) {        // K = 8 * 32
                const int sq = s & 1;            // queue slot (static)
                half8 ah0 = *(const half8*)&RHs[(a0 + s) * 520 + (lane << 3)];
                half8 al0 = *(const half8*)&RLs[(a0 + s) * 520 + (lane << 3)];
                half8 ah1 = *(const half8*)&RHs[(a1 + s) * 520 + (lane << 3)];
                half8 al1 = *(const half8*)&RLs[(a1 + s) * 520 + (lane << 3)];
                // validated chain order per acc: ah*bh ; ah*bl ; al*bh
                acch[0] = MFMA16(ah0, q0h[sq], acch[0]);
                accm[0] = MFMA16(ah0, q0l[sq], accm[0]);
                accm[0] = MFMA16(al0, q0h[sq], accm[0]);
                acch[1] = MFMA16(ah1, q0h[sq], acch[1]);
                accm[1] = MFMA16(ah1, q0l[sq], accm[1]);
                accm[1] = MFMA16(al1, q0h[sq], accm[1]);
                acch[2] = MFMA16(ah0, q1h[sq], acch[2]);
                accm[2] = MFMA16(ah0, q1l[sq], accm[2]);
                accm[2] = MFMA16(al0, q1h[sq], accm[2]);
                acch[3] = MFMA16(ah1, q1h[sq], acch[3]);
                accm[3] = MFMA16(ah1, q1l[sq], accm[3]);
                accm[3] = MFMA16(al1, q1h[sq], accm[3]);
                // refill this slot with packet s+2 (linear; overrun past Bp -> zt, discarded)
                q0h[sq] = *(const half8*)(sp + 0);
                q0l[sq] = *(const half8*)(sp + 512);
                q1h[sq] = *(const half8*)(sp + 1024);
                q1l[sq] = *(const half8*)(sp + 1536);
                sp += 2048;
                __builtin_amdgcn_sched_barrier(0);   // pin the 2-deep window
            }
            // fold: codes ascending (cc asc, f asc) -> strict '>' keeps first max
            #pragma unroll
            for (int f = 0; f < 2; ++f) {
                const int cf = cc * 2 + f;
                const int n = (cq << 8) + (cf << 4) + cl;
                const float hv = h_s[n];
                #pragma unroll
                for (int mfl = 0; mfl < 2; ++mfl)
                    #pragma unroll
                    for (int r = 0; r < 4; ++r) {
                        float sc = acch[f * 2 + mfl][r] + 2.44140625e-4f * accm[f * 2 + mfl][r] - hv;
                        const int sl = mfl * 4 + r;
                        if (sc > v1[sl]) {
                            v2[sl] = v1[sl]; v1[sl] = sc;
                            bc = (bc & ~(15u << (4 * sl))) | ((unsigned)cf << (4 * sl));
                        } else v2[sl] = fmaxf(v2[sl], sc);
                    }
            }
        }
        // reconstruct best-code indices, then reduce top-2 across the 16 lanes
        int n1[8];
        #pragma unroll
        for (int sl = 0; sl < 8; ++sl)
            n1[sl] = (cq << 8) + ((int)((bc >> (4 * sl)) & 15u) << 4) + cl;
        #pragma unroll
        for (int sl = 0; sl < 8; ++sl) {
            #pragma unroll
            for (int mk = 1; mk < 16; mk <<= 1) {
                float o1 = __shfl_xor(v1[sl], mk, 16);
                float o2 = __shfl_xor(v2[sl], mk, 16);
                int   on = __shfl_xor(n1[sl], mk, 16);
                if (o1 > v1[sl] || (o1 == v1[sl] && on < n1[sl])) {
                    v2[sl] = fmaxf(v1[sl], o2);
                    v1[sl] = o1; n1[sl] = on;
                } else {
                    v2[sl] = fmaxf(v2[sl], o1);
                }
            }
        }
        if (cl == 0) {
            #pragma unroll
            for (int sl = 0; sl < 8; ++sl) {
                int t = th * 32 + (sl >> 2) * 16 + g * 4 + (sl & 3);
                cand_v1[cq * TM + t] = v1[sl];
                cand_v2[cq * TM + t] = v2[sl];
                cand_n [cq * TM + t] = n1[sl];
            }
        }
        __syncthreads();
        // combine the four code-quarters (ascending); flag near-ties for exact rescore
        if (tid < TM) {
            float b1v = cand_v1[tid], b2v = cand_v2[tid]; int bn = cand_n[tid];
            #pragma unroll
            for (int ww = 1; ww < 4; ++ww) {
                float o1 = cand_v1[ww * TM + tid], o2 = cand_v2[ww * TM + tid];
                int   on = cand_n[ww * TM + tid];
                if (o1 > b1v) { b2v = fmaxf(b1v, o2); b1v = o1; bn = on; }
                else b2v = fmaxf(b2v, o1);   // ties (o1==b1v) drive gap to 0 -> flagged
            }
            bidx_s[tid] = bn;
            if (b1v - b2v < EPS_GAP) { int p2 = atomicAdd(&nflag, 1); flist[p2] = tid; }
        }
        __syncthreads();
        // exact fp32 rescore (validated numerics: k-ascending single-acc fmaf chain)
        {
            const int nfl = nflag;
            for (int f = w; f < nfl; f += 8) {
                const int t = flist[f];
                const float* rrow = &res_s[t * RSTR];
                float best = -3.4e38f; int bestn = 0;
                for (int i = 0; i < 16; ++i) {
                    const int n = lane + (i << 6);
                    const float* crow = books + ((size_t)b * NE + n) * DDIM;
                    float acc = 0.f;
                    #pragma unroll 4
                    for (int k = 0; k < DDIM; k += 4) {
                        float4 rv = *(const float4*)(rrow + k);
                        float4 cv = *(const float4*)(crow + k);
                        acc = __builtin_fmaf(rv.x, cv.x, acc);
                        acc = __builtin_fmaf(rv.y, cv.y, acc);
                        acc = __builtin_fmaf(rv.z, cv.z, acc);
                        acc = __builtin_fmaf(rv.w, cv.w, acc);
                    }
                    float sc = acc - h_s[n];
                    if (sc > best) { best = sc; bestn = n; }
                }
                #pragma unroll
                for (int mk = 32; mk; mk >>= 1) {
                    float ov = __shfl_xor(best, mk, 64);
                    int   on = __shfl_xor(bestn, mk, 64);
                    if (ov > best || (ov == best && on < bestn)) { best = ov; bestn = on; }
                }
                if (lane == 0) bidx_s[t] = bestn;
            }
        }
        __syncthreads();
        if (tid < TM) idxg[(tok0 + tid) * NB + b] = bidx_s[tid];
        { // residual update r = r - q (plain fp32 subs, matches reference chain)
            int m = tid >> 3, qc = (tid & 7) * 32;
            const float* qrow = books + ((size_t)b * NE + bidx_s[m]) * DDIM + qc;
            float* rrow = &res_s[m * RSTR + qc];
            #pragma unroll
            for (int c2 = 0; c2 < 32; c2 += 4) {
                float4 qv = *(const float4*)(qrow + c2);
                float4 rv2 = *(float4*)(rrow + c2);
                rv2.x = rv2.x - qv.x; rv2.y = rv2.y - qv.y;
                rv2.z = rv2.z - qv.z; rv2.w = rv2.w - qv.w;
                *(float4*)(rrow + c2) = rv2;
            }
        }
    }
}

// ---------- replay: q_sum with the reference's exact fp32 op order (unchanged) ----------
__global__ void replay_kernel(const float* __restrict__ books,
                              const int* __restrict__ idxg,
                              float* __restrict__ zt) {
    size_t gid = (size_t)blockIdx.x * 256 + threadIdx.x;
    size_t tok = gid >> 6;
    int d4 = (int)(gid & 63) * 4;
    const int* ip = idxg + tok * NB;
    float4 r = *(const float4*)&zt[tok * DDIM + d4];
    float4 qs = make_float4(0.f, 0.f, 0.f, 0.f);
    #pragma unroll
    for (int b = 0; b < NB; ++b) {
        int idx = ip[b];
        float4 q = *(const float4*)&books[((size_t)b * NE + idx) * DDIM + d4];
        float t1;
        t1 = q.x - r.x; qs.x = qs.x + t1; qs.x = qs.x + r.x; r.x = r.x - q.x;
        t1 = q.y - r.y; qs.y = qs.y + t1; qs.y = qs.y + r.y; r.y = r.y - q.y;
        t1 = q.z - r.z; qs.z = qs.z + t1; qs.z = qs.z + r.z; r.z = r.z - q.z;
        t1 = q.w - r.w; qs.w = qs.w + t1; qs.w = qs.w + r.w; r.w = r.w - q.w;
    }
    *(float4*)&zt[tok * DDIM + d4] = qs;
}

// ---------- out (B,D,T) = transpose of q_sum[token][dim] (unchanged) ----------
__global__ void fin_kernel(const float* __restrict__ qst, float* __restrict__ out) {
    __shared__ float ld[64 * 68];
    int t0 = blockIdx.x * 64, d0 = blockIdx.y * 64, b = blockIdx.z;
    int tid = threadIdx.x;
    {
        int t = tid >> 2, d4 = (tid & 3) * 16;
        const float* rp = qst + ((size_t)b * TTOK + t0 + t) * DDIM + d0 + d4;
        #pragma unroll
        for (int c = 0; c < 16; c += 4)
            *(float4*)&ld[t * 68 + d4 + c] = *(const float4*)(rp + c);
    }
    __syncthreads();
    {
        int dd = tid >> 2, t4 = (tid & 3) * 16;
        float* op = out + ((size_t)b * DDIM + d0 + dd) * TTOK + t0 + t4;
        #pragma unroll
        for (int c = 0; c < 16; c += 4) {
            float4 o;
            o.x = ld[(size_t)(t4 + c + 0) * 68 + dd];
            o.y = ld[(size_t)(t4 + c + 1) * 68 + dd];
            o.z = ld[(size_t)(t4 + c + 2) * 68 + dd];
            o.w = ld[(size_t)(t4 + c + 3) * 68 + dd];
            *(float4*)(op + c) = o;
        }
    }
}

extern "C" void kernel_launch(void* const* d_in, const int* in_sizes, int n_in,
                              void* d_out, int out_size, void* d_ws, size_t ws_size,
                              hipStream_t stream) {
    const float* z     = (const float*)d_in[0];
    const float* books = (const float*)d_in[1];
    float* out = (float*)d_out;

    float* hg    = (float*)d_ws;                         // 8192 floats
    int*   idxg  = (int*)(hg + (size_t)NB * NE);         // 65536*8 ints (2 MB)
    _Float16* Bp = (_Float16*)(idxg + (size_t)NTOK * NB);// 8 MB stream-ordered fragments
    float* zt    = (float*)(Bp + (size_t)NB * NE * DDIM * 2); // 64 MB token-major
    // NOTE: vq_main's rolling 2-deep prefetch reads <=8KB past Bp's end -> zt, discarded.

    hsum_kernel<<<(NB * NE + 255) / 256, 256, 0, stream>>>(books, hg);
    bfrag_kernel<<<(NB * 64 * 8 * 64) / 256, 256, 0, stream>>>(books, Bp);
    txin_kernel<<<dim3(TTOK / 64, DDIM / 64, BBATCH), 256, 0, stream>>>(z, zt);
    vq_main<<<NTOK / TM, 512, 0, stream>>>(books, Bp, hg, zt, idxg);
    replay_kernel<<<NTOK * 64 / 256, 256, 0, stream>>>(books, idxg, zt);
    fin_kernel<<<dim3(TTOK / 64, DDIM / 64, BBATCH), 256, 0, stream>>>(zt, out);
}